// Round 9
// baseline (356.087 us; speedup 1.0000x reference)
//
#include <hip/hip_runtime.h>

// ActorCritic fused kernel R12 (= R11 resubmitted; Round-8 run died to an
// infra/container failure with no counters; audit found no kernel fault:
// 26KB LDS, uniform barriers, closed Hbuf parity, 3-barrier Axg separation,
// static indexing throughout).
//
// R10 post-mortem: step is ISSUE-bound and modeled exactly:
// per SIMD: matrix = 2 waves x 20 MFMA x 19.4cy = 776cy; VALU ~550cy; they
// ADD (not overlap) because the 2 waves/SIMD are barrier-lockstepped -- both
// are in the MFMA block, then both in the activation block. 776+550+LDS/bar
// = 1620cy measured. This kernel (all register-neutral; at the 256-reg cap):
//  - SPLIT STEP: issue gates(i,f) MFMAs -> activation(i,f) -> gates(g,o)
//    MFMAs -> activation(g,o)+cell+write. A wave reaches act(i,f) after only
//    8 MFMAs while the other wave's MFMAs keep the matrix pipe busy ->
//    activation VALU hides under matrix time instead of adding to it.
//  - DUAL SUB-CHAINS per gate (2 chains of depth 2 + scalar add): 4
//    independent MFMA streams per half-step -> less dependent-MFMA wait.
//  - GROUP-OF-4 phase: P[4] (16 regs). Phase MFMA rate unchanged (16 MFMAs
//    per 4 steps). Staging: 1 float4 load @ i==1, 1 f16x4 LDS write @ i==3;
//    single Axg buffer (phase read and i==3 overwrite are 3 barriers apart).

typedef _Float16 f16x8 __attribute__((ext_vector_type(8)));
typedef _Float16 f16x4 __attribute__((ext_vector_type(4)));
typedef float    f32x4 __attribute__((ext_vector_type(4)));

#define NLOG2E (-1.4426950408889634f)

__device__ __forceinline__ float rcpf(float x) { return __builtin_amdgcn_rcpf(x); }
__device__ __forceinline__ float ex2(float x)  { return __builtin_amdgcn_exp2f(x); }

__device__ __forceinline__ f16x4 pack4(const float4 a) {
    f16x4 v;
    v[0] = (_Float16)a.x; v[1] = (_Float16)a.y;
    v[2] = (_Float16)a.z; v[3] = (_Float16)a.w;
    return v;
}

__global__ __launch_bounds__(512, 2)
void ac_fused(const float* __restrict__ hin,
              const float* __restrict__ Wx, const float* __restrict__ Wh,
              const float* __restrict__ bh,
              const float* __restrict__ Wa1, const float* __restrict__ ba1,
              const float* __restrict__ Wa2, const float* __restrict__ ba2,
              const float* __restrict__ Wa3, const float* __restrict__ ba3,
              const float* __restrict__ logstd,
              const float* __restrict__ Wc1, const float* __restrict__ bc1,
              const float* __restrict__ Wc2, const float* __restrict__ bc2,
              const float* __restrict__ Wc3, const float* __restrict__ bc3,
              float* __restrict__ out)
{
    constexpr int T = 256, F = 128, H = 128, G = 512; // G = 4*H

    // Compact per-row h buffers (R9): Hbuf[buf][kq][r] = f16x8 chunk
    // h[batch r][kq*8..+7]. Fragment for lane (q,m16) at kt:
    // Hbuf[buf][kt*4+q][m16>>2].
    __shared__ f16x8 Hbuf[2][16][4];    // 2 x 1 KB
    // x-tile for the current 4-step group (ONE Mtile, fragment order):
    // row m <-> x[batch m>>2][t0 + (m&3)].
    __shared__ f16x8 Axg[256];          // 4 KB
    __shared__ float xf[4][F + 1];      // final hidden (fp32)
    __shared__ float hb1[2][4][257];    // L1 out: [actor/critic][row][n]
    __shared__ float hb2[2][4][257];    // L2 out
    __shared__ float redA[4][8][8];     // actor L3 partials
    __shared__ float redC[4][32];       // critic L3 partials

    const int tid  = threadIdx.x;
    const int lane = tid & 63;
    const int wv   = tid >> 6;    // wave 0..7
    const int m16  = lane & 15;
    const int q    = lane >> 4;   // quad 0..3
    const int r0   = blockIdx.x << 2;
    const int ncol = (wv << 4) + m16;   // this wave/lane's output column per gate

    // ---- load weight B-fragments into registers (-> AGPRs) ----
    f16x8 bwx[4][4], bwh[4][4];
    #pragma unroll
    for (int kt = 0; kt < 4; ++kt) {
        #pragma unroll
        for (int s = 0; s < 4; ++s) {
            f16x8 vx, vh;
            #pragma unroll
            for (int j = 0; j < 8; ++j) {
                const int k = (kt << 5) + (q << 3) + j;   // 0..127
                vx[j] = (_Float16)Wx[k * G + s * H + ncol];
                vh[j] = (_Float16)Wh[k * G + s * H + ncol];
            }
            bwx[s][kt] = vx;
            bwh[s][kt] = vh;
        }
    }
    // bias terms for the folded activation: sig(z+b) = rcp(1 + 2^(z*NLOG2E + nb))
    const float nbi = NLOG2E * bh[0 * H + ncol];
    const float nbf = NLOG2E * bh[1 * H + ncol];
    const float nbg = 2.0f * NLOG2E * bh[2 * H + ncol];
    const float nbo = NLOG2E * bh[3 * H + ncol];

    const f32x4 zq = {0.f, 0.f, 0.f, 0.f};   // persistent MFMA zero-C quad

    // ---- x staging ids: thread stages chunk xc = tid>>1, half xh = tid&1.
    //      chunk row m = xc&15 -> batch (xc>>2)&3, tsub = xc&3. ----
    const int xc = tid >> 1;
    const int xh = tid & 1;
    const int xk0 = ((xc >> 6) << 5) + (((xc >> 4) & 3) << 3) + (xh << 2);
    const float* pgbase = hin + (size_t)(r0 + ((xc >> 2) & 3)) * T * F
                              + (size_t)(xc & 3) * F + xk0;

    // h fragment-read base (chunk units): index = kt*16 + (q*4 + (m16>>2))
    const int hr0 = (q << 2) + (m16 >> 2);
    // h-write halfword index: chunk kq=ncol>>3, row q, j=ncol&7
    const int hw  = ((((ncol >> 3) << 2) + q) << 3) + (ncol & 7);

    // ---- zero h buffers (h_{-1} = 0) ----
    if (tid < 128) {
        f16x8 zz = {};
        ((f16x8*)Hbuf)[tid] = zz;
    }

    // ---- prologue: load + stage group-0 x-tile (t = 0..3) ----
    {
        const float4 xp0 = *(const float4*)(pgbase);
        __syncthreads();   // Hbuf zeros visible; Axg not yet read by anyone
        *(f16x4*)((_Float16*)&Axg[0] + xc * 8 + xh * 4) = pack4(xp0);
    }
    asm volatile("s_waitcnt lgkmcnt(0)" ::: "memory");
    __builtin_amdgcn_s_barrier();

    float cstate = 0.0f;
    float hcur   = 0.0f;

    for (int t0 = 0; t0 < T; t0 += 4) {
        // ========== PHASE: P[s] = x-tile @ Wx (group-of-4 xg in registers) ==========
        // Lane (q,m16): P[s][reg] = xg[batch q][t0+reg][s*H+ncol], reg = step.
        f32x4 P[4];
        {
            const f16x8 fr = Axg[lane];
            P[0] = __builtin_amdgcn_mfma_f32_16x16x32_f16(fr, bwx[0][0], zq, 0, 0, 0);
            P[1] = __builtin_amdgcn_mfma_f32_16x16x32_f16(fr, bwx[1][0], zq, 0, 0, 0);
            P[2] = __builtin_amdgcn_mfma_f32_16x16x32_f16(fr, bwx[2][0], zq, 0, 0, 0);
            P[3] = __builtin_amdgcn_mfma_f32_16x16x32_f16(fr, bwx[3][0], zq, 0, 0, 0);
        }
        #pragma unroll
        for (int kt = 1; kt < 4; ++kt) {
            const f16x8 fr = Axg[(kt << 6) + lane];
            P[0] = __builtin_amdgcn_mfma_f32_16x16x32_f16(fr, bwx[0][kt], P[0], 0, 0, 0);
            P[1] = __builtin_amdgcn_mfma_f32_16x16x32_f16(fr, bwx[1][kt], P[1], 0, 0, 0);
            P[2] = __builtin_amdgcn_mfma_f32_16x16x32_f16(fr, bwx[2][kt], P[2], 0, 0, 0);
            P[3] = __builtin_amdgcn_mfma_f32_16x16x32_f16(fr, bwx[3][kt], P[3], 0, 0, 0);
        }
        // fold scale+bias vectorwise: Pn = P*c_s + nb_s
        P[0] = P[0] * NLOG2E          + f32x4{nbi, nbi, nbi, nbi};
        P[1] = P[1] * NLOG2E          + f32x4{nbf, nbf, nbf, nbf};
        P[2] = P[2] * (2.0f * NLOG2E) + f32x4{nbg, nbg, nbg, nbg};
        P[3] = P[3] * NLOG2E          + f32x4{nbo, nbo, nbo, nbo};

        // ========== 4 steady steps (h recurrence only) ==========
        float4 xpn;
        #pragma unroll
        for (int i = 0; i < 4; ++i) {
            const f16x8* Hc = &Hbuf[i & 1][0][0];          // holds h_{t-1}
            _Float16*    Hn = (_Float16*)&Hbuf[(i + 1) & 1][0][0];

            // A-fragments first (chain head)
            const f16x8 af0 = Hc[hr0];
            const f16x8 af1 = Hc[16 + hr0];
            const f16x8 af2 = Hc[32 + hr0];
            const f16x8 af3 = Hc[48 + hr0];

            // issue next-group x load early (consumed at i==3; ~2 steps cover,
            // x is L2/L3-resident after the first pass)
            if (i == 1) {
                const int t0n = (t0 + 4 < T) ? t0 + 4 : t0;
                xpn = *(const float4*)(pgbase + (size_t)t0n * F);
            }

            // ---- half 1: gates i,f as 4 independent depth-2 sub-chains ----
            f32x4 ci0 = __builtin_amdgcn_mfma_f32_16x16x32_f16(af0, bwh[0][0], zq, 0, 0, 0);
            f32x4 ci1 = __builtin_amdgcn_mfma_f32_16x16x32_f16(af2, bwh[0][2], zq, 0, 0, 0);
            f32x4 cf0 = __builtin_amdgcn_mfma_f32_16x16x32_f16(af0, bwh[1][0], zq, 0, 0, 0);
            f32x4 cf1 = __builtin_amdgcn_mfma_f32_16x16x32_f16(af2, bwh[1][2], zq, 0, 0, 0);
            ci0 = __builtin_amdgcn_mfma_f32_16x16x32_f16(af1, bwh[0][1], ci0, 0, 0, 0);
            ci1 = __builtin_amdgcn_mfma_f32_16x16x32_f16(af3, bwh[0][3], ci1, 0, 0, 0);
            cf0 = __builtin_amdgcn_mfma_f32_16x16x32_f16(af1, bwh[1][1], cf0, 0, 0, 0);
            cf1 = __builtin_amdgcn_mfma_f32_16x16x32_f16(af3, bwh[1][3], cf1, 0, 0, 0);

            // act(i,f) -- overlaps the other wave's matrix work
            const float iv = rcpf(1.0f + ex2(fmaf(ci0[0] + ci1[0], NLOG2E, P[0][i])));
            const float fv = rcpf(1.0f + ex2(fmaf(cf0[0] + cf1[0], NLOG2E, P[1][i])));

            // ---- half 2: gates g,o ----
            f32x4 cg0 = __builtin_amdgcn_mfma_f32_16x16x32_f16(af0, bwh[2][0], zq, 0, 0, 0);
            f32x4 cg1 = __builtin_amdgcn_mfma_f32_16x16x32_f16(af2, bwh[2][2], zq, 0, 0, 0);
            f32x4 co0 = __builtin_amdgcn_mfma_f32_16x16x32_f16(af0, bwh[3][0], zq, 0, 0, 0);
            f32x4 co1 = __builtin_amdgcn_mfma_f32_16x16x32_f16(af2, bwh[3][2], zq, 0, 0, 0);
            cg0 = __builtin_amdgcn_mfma_f32_16x16x32_f16(af1, bwh[2][1], cg0, 0, 0, 0);
            cg1 = __builtin_amdgcn_mfma_f32_16x16x32_f16(af3, bwh[2][3], cg1, 0, 0, 0);
            co0 = __builtin_amdgcn_mfma_f32_16x16x32_f16(af1, bwh[3][1], co0, 0, 0, 0);
            co1 = __builtin_amdgcn_mfma_f32_16x16x32_f16(af3, bwh[3][3], co1, 0, 0, 0);

            const float gv = 2.0f * rcpf(1.0f + ex2(fmaf(cg0[0] + cg1[0], 2.0f * NLOG2E, P[2][i]))) - 1.0f;
            const float ov = rcpf(1.0f + ex2(fmaf(co0[0] + co1[0], NLOG2E, P[3][i])));
            cstate = fv * cstate + iv * gv;
            const float th = 2.0f * rcpf(1.0f + ex2(cstate * (2.0f * NLOG2E))) - 1.0f;
            hcur = ov * th;

            // h_t -> compact next buffer: ONE b16 write per lane
            Hn[hw] = (_Float16)hcur;

            // stage next group's x-tile (load issued at i==1) before barrier
            if (i == 3) {
                *(f16x4*)((_Float16*)&Axg[0] + xc * 8 + xh * 4) = pack4(xpn);
            }

            asm volatile("s_waitcnt lgkmcnt(0)" ::: "memory");
            __builtin_amdgcn_s_barrier();
        }
    }

    // ---- final hidden (fp32, pre-rounding) to LDS for the heads ----
    xf[q][ncol] = hcur;
    __syncthreads();

    // ---- MLP heads: actor (tid<256) and critic (tid>=256) concurrently ----
    const int half = tid >> 8;          // 0 = actor, 1 = critic
    const int n    = tid & 255;
    const float* W1 = half ? Wc1 : Wa1;
    const float* b1 = half ? bc1 : ba1;
    const float* W2 = half ? Wc2 : Wa2;
    const float* b2 = half ? bc2 : ba2;

    auto tanhl = [&](float x) { return 2.0f * rcpf(1.0f + ex2(x * (2.0f * NLOG2E))) - 1.0f; };

    {   // L1: K=128, 4 rows/thread
        float a0, a1, a2, a3;
        const float b = b1[n];
        a0 = a1 = a2 = a3 = b;
        #pragma unroll 16
        for (int k = 0; k < 128; ++k) {
            const float w = W1[k * 256 + n];
            a0 += xf[0][k] * w; a1 += xf[1][k] * w;
            a2 += xf[2][k] * w; a3 += xf[3][k] * w;
        }
        hb1[half][0][n] = tanhl(a0); hb1[half][1][n] = tanhl(a1);
        hb1[half][2][n] = tanhl(a2); hb1[half][3][n] = tanhl(a3);
    }
    __syncthreads();
    {   // L2: K=256, 4 rows/thread
        float a0, a1, a2, a3;
        const float b = b2[n];
        a0 = a1 = a2 = a3 = b;
        #pragma unroll 16
        for (int k = 0; k < 256; ++k) {
            const float w = W2[k * 256 + n];
            a0 += hb1[half][0][k] * w; a1 += hb1[half][1][k] * w;
            a2 += hb1[half][2][k] * w; a3 += hb1[half][3][k] * w;
        }
        hb2[half][0][n] = tanhl(a0); hb2[half][1][n] = tanhl(a1);
        hb2[half][2][n] = tanhl(a2); hb2[half][3][n] = tanhl(a3);
    }
    __syncthreads();
    if (tid < 256) {        // actor L3 partials: (r, aa, seg) x K-chunk of 32
        const int r = tid >> 6, aa = (tid >> 3) & 7, seg = tid & 7;
        float acc = 0.0f;
        const int k0 = seg << 5;
        #pragma unroll 16
        for (int k = k0; k < k0 + 32; ++k) acc += hb2[0][r][k] * Wa3[k * 8 + aa];
        redA[r][aa][seg] = acc;
    } else if (tid < 384) { // critic L3 partials: (r, seg) x K-chunk of 8
        const int u = tid - 256;
        const int r = u >> 5, seg = u & 31;
        float acc = 0.0f;
        const int k0 = seg << 3;
        #pragma unroll
        for (int k = k0; k < k0 + 8; ++k) acc += hb2[1][r][k] * Wc3[k];
        redC[r][seg] = acc;
    }
    __syncthreads();
    if (tid < 32) {                                              // actor out
        const int r = tid >> 3, aa = tid & 7;
        float acc = ba3[aa];
        #pragma unroll
        for (int s = 0; s < 8; ++s) acc += redA[r][aa][s];
        out[(size_t)(r0 + r) * 17 + aa]     = acc;
        out[(size_t)(r0 + r) * 17 + 8 + aa] = __expf(logstd[aa]);
    } else if (tid >= 64 && tid < 68) {                          // critic out
        const int r = tid - 64;
        float acc = bc3[0];
        #pragma unroll
        for (int s = 0; s < 32; ++s) acc += redC[r][s];
        out[(size_t)(r0 + r) * 17 + 16] = acc;
    }
}

extern "C" void kernel_launch(void* const* d_in, const int* in_sizes, int n_in,
                              void* d_out, int out_size, void* d_ws, size_t ws_size,
                              hipStream_t stream) {
    (void)in_sizes; (void)n_in; (void)d_ws; (void)ws_size; (void)out_size;
    const float* hin = (const float*)d_in[0];
    const float* Wx  = (const float*)d_in[1];
    const float* Wh  = (const float*)d_in[2];
    const float* bh  = (const float*)d_in[3];
    const float* Wa1 = (const float*)d_in[4];
    const float* ba1 = (const float*)d_in[5];
    const float* Wa2 = (const float*)d_in[6];
    const float* ba2 = (const float*)d_in[7];
    const float* Wa3 = (const float*)d_in[8];
    const float* ba3 = (const float*)d_in[9];
    const float* ls  = (const float*)d_in[10];
    const float* Wc1 = (const float*)d_in[11];
    const float* bc1 = (const float*)d_in[12];
    const float* Wc2 = (const float*)d_in[13];
    const float* bc2 = (const float*)d_in[14];
    const float* Wc3 = (const float*)d_in[15];
    const float* bc3 = (const float*)d_in[16];

    hipLaunchKernelGGL(ac_fused, dim3(256), dim3(512), 0, stream,
                       hin, Wx, Wh, bh, Wa1, ba1, Wa2, ba2, Wa3, ba3, ls,
                       Wc1, bc1, Wc2, bc2, Wc3, bc3, (float*)d_out);
}